// Round 10
// baseline (238.716 us; speedup 1.0000x reference)
//
#include <hip/hip_runtime.h>
#include <math.h>
#include <limits.h>
#include <stdint.h>

namespace {
constexpr int G = 16;    // num_graphs
constexpr int N = 2048;  // num_nodes
constexpr int K = 16;    // k_neighs
constexpr int C = 20;    // candidates per side (K + diag exclusion + tie slack)
typedef float floatx4 __attribute__((ext_vector_type(4)));
}

// 2*G blocks, 1 wave each. Block b: g=b>>1, side=b&1 (0: largest t, 1: smallest t).
// Register-resident selection via lexicographic cursor. Also emits the 64-word
// base top-16 mask and the (t_c15, t_c16) boundary pair for the tie test.
__global__ void topk_kernel(const float* __restrict__ emb_t,
                            int* __restrict__ candidx /* [2G][C] */,
                            float* __restrict__ boundary /* [2G][2] */,
                            unsigned* __restrict__ basemask /* [2G][64] */) {
    const int g = blockIdx.x >> 1;
    const int side = blockIdx.x & 1;
    const int lane = threadIdx.x;            // 64 = one wave
    const float sgn = side ? -1.f : 1.f;     // negate for min side -> always argmax

    float v[32];
    #pragma unroll
    for (int m = 0; m < 32; ++m) v[m] = sgn * emb_t[g * N + lane + 64 * m];

    float pv = INFINITY; int pi = -1;        // lexicographic cursor
    unsigned mw = 0;                          // this lane's base-mask word
    float b15 = 0.f, b16 = 0.f;
    for (int p = 0; p < C; ++p) {
        float bv = -INFINITY; int bi = INT_MAX;
        #pragma unroll
        for (int m = 0; m < 32; ++m) {
            const int idx = lane + 64 * m;
            const float x = v[m];
            const bool elig = (x < pv) || (x == pv && idx > pi);
            if (elig && (x > bv || (x == bv && idx < bi))) { bv = x; bi = idx; }
        }
        #pragma unroll
        for (int off = 32; off >= 1; off >>= 1) {
            const float ov = __shfl_xor(bv, off);
            const int   oi = __shfl_xor(bi, off);
            if (ov > bv || (ov == bv && oi < bi)) { bv = ov; bi = oi; }
        }
        if (lane == 0) candidx[blockIdx.x * C + p] = bi;
        if (p < K && (bi >> 5) == lane) mw |= 1u << (bi & 31);
        if (p == 15) b15 = bv;
        if (p == 16) b16 = bv;
        pv = bv; pi = bi;
    }
    basemask[blockIdx.x * 64 + lane] = mw;
    if (lane == 0) {
        boundary[blockIdx.x * 2 + 0] = sgn * b15;   // original t values
        boundary[blockIdx.x * 2 + 1] = sgn * b16;
    }
}

// One lane per row: compress sign + "may deviate from base mask" into bitmasks.
__global__ __launch_bounds__(256) void prep_kernel(
    const float* __restrict__ emb_s,
    const float* __restrict__ boundary,
    const unsigned* __restrict__ basemask,
    unsigned* __restrict__ signw /* [G*N/32] */,
    unsigned* __restrict__ specialw /* [G*N/32] */) {
    const int lane = threadIdx.x & 63;
    const int wid = blockIdx.x * 4 + (threadIdx.x >> 6);   // 0..511, 64 rows each
    const int row = wid * 64 + lane;
    const int g = row >> 11;
    const int i = row & (N - 1);
    const float s = emb_s[row];
    const bool sneg = __float_as_int(s) < 0;
    const int tb = 2 * g + (sneg ? 1 : 0);
    const unsigned w = basemask[tb * 64 + (i >> 5)];
    const bool inTop = (w >> (i & 31)) & 1u;
    const float a = boundary[tb * 2 + 0];
    const float b = boundary[tb * 2 + 1];
    const bool special = (s == 0.0f) || inTop || (s * a == s * b);
    const unsigned long long sm = __ballot(sneg);
    const unsigned long long pm = __ballot(special);
    if (lane == 0) {
        signw[wid * 2 + 0] = (unsigned)sm;
        signw[wid * 2 + 1] = (unsigned)(sm >> 32);
        specialw[wid * 2 + 0] = (unsigned)pm;
        specialw[wid * 2 + 1] = (unsigned)(pm >> 32);
    }
}

// Exact per-row mask (proven logic) — only for flagged rows.
__device__ __forceinline__ unsigned row_word(const float* __restrict__ emb_s,
                                             const float* __restrict__ emb_t,
                                             const int* __restrict__ candidx,
                                             int row, int lane) {
    const int g = row >> 11;
    const int i = row & (N - 1);
    const float s = emb_s[row];

    int idx = INT_MAX;
    bool sel = false;
    if (s != 0.0f) {
        const int* list = candidx + (g * 2 + (s < 0.0f)) * C;
        float p = -INFINITY;
        if (lane < C) {
            idx = list[lane];
            p = s * emb_t[g * N + idx];
            if (idx == i) { p = -INFINITY; idx = INT_MAX; }
        }
        int rank = 0;
        for (int c = 0; c < C; ++c) {
            const float pc = __shfl(p, c);
            const int   ic = __shfl(idx, c);
            if (pc > p || (pc == p && ic < idx)) ++rank;
        }
        sel = (lane < C) && (rank < K) && (idx != INT_MAX);
    } else {
        if (lane < K) {
            const int pos = (i < K + 1) ? i : (K + 1);
            idx = (lane < pos) ? lane : lane + 1;
            sel = true;
        }
    }

    unsigned word = 0;
    for (int c = 0; c < C; ++c) {
        const int ic = __shfl(idx, c);
        const int sc = __shfl((int)sel, c);
        if (sc && (ic >> 5) == lane) word |= 1u << (ic & 31);
    }
    return word;
}

// Bulk writer (R9-identical, destination parameterized): per wave, build both
// row images in registers once, then 16 rows x 8 regular dwordx4 stores.
__global__ __launch_bounds__(256) void fill_kernel(
    const float* __restrict__ emb_s,
    const float* __restrict__ emb_t,
    const int* __restrict__ candidx,
    const unsigned* __restrict__ basemask,
    const unsigned* __restrict__ signw,
    const unsigned* __restrict__ specialw,
    float* __restrict__ dst)
{
    const int lane = threadIdx.x & 63;
    const int wave = threadIdx.x >> 6;
    const int rowbase = blockIdx.x * 64 + wave * 16;   // 16 consecutive rows
    const int g = rowbase >> 11;

    const unsigned sw = __builtin_amdgcn_readfirstlane(signw[rowbase >> 5]) >> (rowbase & 31);
    const unsigned pw = __builtin_amdgcn_readfirstlane(specialw[rowbase >> 5]) >> (rowbase & 31);

    const unsigned wpos = basemask[(2 * g + 0) * 64 + lane];
    const unsigned wneg = basemask[(2 * g + 1) * 64 + lane];
    floatx4 pos[8], neg[8];
    #pragma unroll
    for (int c = 0; c < 8; ++c) {
        const unsigned wp = (unsigned)__shfl((int)wpos, c * 8 + (lane >> 3));
        const unsigned wn = (unsigned)__shfl((int)wneg, c * 8 + (lane >> 3));
        const int b0 = (lane & 7) * 4;
        pos[c].x = (float)((wp >> (b0 + 0)) & 1u);
        pos[c].y = (float)((wp >> (b0 + 1)) & 1u);
        pos[c].z = (float)((wp >> (b0 + 2)) & 1u);
        pos[c].w = (float)((wp >> (b0 + 3)) & 1u);
        neg[c].x = (float)((wn >> (b0 + 0)) & 1u);
        neg[c].y = (float)((wn >> (b0 + 1)) & 1u);
        neg[c].z = (float)((wn >> (b0 + 2)) & 1u);
        neg[c].w = (float)((wn >> (b0 + 3)) & 1u);
    }

    #pragma unroll 1
    for (int r = 0; r < 16; ++r) {
        const int row = rowbase + r;
        floatx4* rp = reinterpret_cast<floatx4*>(dst + (size_t)row * N);
        if ((pw >> r) & 1u) {
            const unsigned word = row_word(emb_s, emb_t, candidx, row, lane);
            #pragma unroll
            for (int c = 0; c < 8; ++c) {
                const unsigned w = (unsigned)__shfl((int)word, c * 8 + (lane >> 3));
                const int b0 = (lane & 7) * 4;
                floatx4 v;
                v.x = (float)((w >> (b0 + 0)) & 1u);
                v.y = (float)((w >> (b0 + 1)) & 1u);
                v.z = (float)((w >> (b0 + 2)) & 1u);
                v.w = (float)((w >> (b0 + 3)) & 1u);
                *(rp + c * 64 + lane) = v;
            }
        } else if ((sw >> r) & 1u) {
            #pragma unroll
            for (int c = 0; c < 8; ++c)
                *(rp + c * 64 + lane) = neg[c];
        } else {
            #pragma unroll
            for (int c = 0; c < 8; ++c)
                *(rp + c * 64 + lane) = pos[c];
        }
    }
}

extern "C" void kernel_launch(void* const* d_in, const int* in_sizes, int n_in,
                              void* d_out, int out_size, void* d_ws, size_t ws_size,
                              hipStream_t stream) {
    const float* emb_s = (const float*)d_in[0];   // (G, N, 1) f32
    const float* emb_t = (const float*)d_in[1];   // (G, 1, N) f32
    float* out = (float*)d_out;                   // (G, N, N) f32

    const size_t outBytes = (size_t)G * N * N * sizeof(float);   // 256 MiB
    const size_t metaOff = outBytes;                              // meta after stage
    const size_t needStage = outBytes + 32768;

    char* wsb = (char*)d_ws;

    if (ws_size >= needStage) {
        // Probe path: build output in d_ws (fast buffer), then SDMA/blit to d_out.
        float* stage        = (float*)wsb;
        int* candidx        = (int*)(wsb + metaOff);
        float* boundary     = (float*)(wsb + metaOff + 4096);
        unsigned* basemask  = (unsigned*)(wsb + metaOff + 8192);
        unsigned* signw     = (unsigned*)(wsb + metaOff + 16384);
        unsigned* specialw  = (unsigned*)(wsb + metaOff + 20480);

        topk_kernel<<<2 * G, 64, 0, stream>>>(emb_t, candidx, boundary, basemask);
        prep_kernel<<<128, 256, 0, stream>>>(emb_s, boundary, basemask, signw, specialw);
        fill_kernel<<<G * N / 64, 256, 0, stream>>>(emb_s, emb_t, candidx, basemask,
                                                    signw, specialw, stage);
        hipMemcpyAsync(out, stage, outBytes, hipMemcpyDeviceToDevice, stream);
    } else {
        // R9 path (proven 107 µs): fill d_out directly.
        int* candidx        = (int*)wsb;
        float* boundary     = (float*)(wsb + 4096);
        unsigned* basemask  = (unsigned*)(wsb + 8192);
        unsigned* signw     = (unsigned*)(wsb + 16384);
        unsigned* specialw  = (unsigned*)(wsb + 20480);

        topk_kernel<<<2 * G, 64, 0, stream>>>(emb_t, candidx, boundary, basemask);
        prep_kernel<<<128, 256, 0, stream>>>(emb_s, boundary, basemask, signw, specialw);
        fill_kernel<<<G * N / 64, 256, 0, stream>>>(emb_s, emb_t, candidx, basemask,
                                                    signw, specialw, out);
    }
}

// Round 11
// 184.264 us; speedup vs baseline: 1.2955x; 1.2955x over previous
//
#include <hip/hip_runtime.h>
#include <math.h>
#include <limits.h>
#include <stdint.h>

namespace {
constexpr int G = 16;    // num_graphs
constexpr int N = 2048;  // num_nodes
constexpr int K = 16;    // k_neighs
constexpr int C = 20;    // candidates per side (K + diag exclusion + tie slack)
typedef float floatx4 __attribute__((ext_vector_type(4)));
}

// 2*G blocks, 1 wave each. Block b: g=b>>1, side=b&1 (0: largest t, 1: smallest t).
__global__ void topk_kernel(const float* __restrict__ emb_t,
                            int* __restrict__ candidx /* [2G][C] */,
                            float* __restrict__ boundary /* [2G][2] */,
                            unsigned* __restrict__ basemask /* [2G][64] */) {
    const int g = blockIdx.x >> 1;
    const int side = blockIdx.x & 1;
    const int lane = threadIdx.x;            // 64 = one wave
    const float sgn = side ? -1.f : 1.f;     // negate for min side -> always argmax

    float v[32];
    #pragma unroll
    for (int m = 0; m < 32; ++m) v[m] = sgn * emb_t[g * N + lane + 64 * m];

    float pv = INFINITY; int pi = -1;        // lexicographic cursor
    unsigned mw = 0;                          // this lane's base-mask word
    float b15 = 0.f, b16 = 0.f;
    for (int p = 0; p < C; ++p) {
        float bv = -INFINITY; int bi = INT_MAX;
        #pragma unroll
        for (int m = 0; m < 32; ++m) {
            const int idx = lane + 64 * m;
            const float x = v[m];
            const bool elig = (x < pv) || (x == pv && idx > pi);
            if (elig && (x > bv || (x == bv && idx < bi))) { bv = x; bi = idx; }
        }
        #pragma unroll
        for (int off = 32; off >= 1; off >>= 1) {
            const float ov = __shfl_xor(bv, off);
            const int   oi = __shfl_xor(bi, off);
            if (ov > bv || (ov == bv && oi < bi)) { bv = ov; bi = oi; }
        }
        if (lane == 0) candidx[blockIdx.x * C + p] = bi;
        if (p < K && (bi >> 5) == lane) mw |= 1u << (bi & 31);
        if (p == 15) b15 = bv;
        if (p == 16) b16 = bv;
        pv = bv; pi = bi;
    }
    basemask[blockIdx.x * 64 + lane] = mw;
    if (lane == 0) {
        boundary[blockIdx.x * 2 + 0] = sgn * b15;   // original t values
        boundary[blockIdx.x * 2 + 1] = sgn * b16;
    }
}

// One lane per row: compress sign + "may deviate from base mask" into bitmasks.
__global__ __launch_bounds__(256) void prep_kernel(
    const float* __restrict__ emb_s,
    const float* __restrict__ boundary,
    const unsigned* __restrict__ basemask,
    unsigned* __restrict__ signw /* [G*N/32] */,
    unsigned* __restrict__ specialw /* [G*N/32] */) {
    const int lane = threadIdx.x & 63;
    const int wid = blockIdx.x * 4 + (threadIdx.x >> 6);   // 0..511, 64 rows each
    const int row = wid * 64 + lane;
    const int g = row >> 11;
    const int i = row & (N - 1);
    const float s = emb_s[row];
    const bool sneg = __float_as_int(s) < 0;
    const int tb = 2 * g + (sneg ? 1 : 0);
    const unsigned w = basemask[tb * 64 + (i >> 5)];
    const bool inTop = (w >> (i & 31)) & 1u;
    const float a = boundary[tb * 2 + 0];
    const float b = boundary[tb * 2 + 1];
    const bool special = (s == 0.0f) || inTop || (s * a == s * b);
    const unsigned long long sm = __ballot(sneg);
    const unsigned long long pm = __ballot(special);
    if (lane == 0) {
        signw[wid * 2 + 0] = (unsigned)sm;
        signw[wid * 2 + 1] = (unsigned)(sm >> 32);
        specialw[wid * 2 + 0] = (unsigned)pm;
        specialw[wid * 2 + 1] = (unsigned)(pm >> 32);
    }
}

// Exact per-row mask (proven logic) — only for flagged rows.
__device__ __forceinline__ unsigned row_word(const float* __restrict__ emb_s,
                                             const float* __restrict__ emb_t,
                                             const int* __restrict__ candidx,
                                             int row, int lane) {
    const int g = row >> 11;
    const int i = row & (N - 1);
    const float s = emb_s[row];

    int idx = INT_MAX;
    bool sel = false;
    if (s != 0.0f) {
        const int* list = candidx + (g * 2 + (s < 0.0f)) * C;
        float p = -INFINITY;
        if (lane < C) {
            idx = list[lane];
            p = s * emb_t[g * N + idx];
            if (idx == i) { p = -INFINITY; idx = INT_MAX; }
        }
        int rank = 0;
        for (int c = 0; c < C; ++c) {
            const float pc = __shfl(p, c);
            const int   ic = __shfl(idx, c);
            if (pc > p || (pc == p && ic < idx)) ++rank;
        }
        sel = (lane < C) && (rank < K) && (idx != INT_MAX);
    } else {
        if (lane < K) {
            const int pos = (i < K + 1) ? i : (K + 1);
            idx = (lane < pos) ? lane : lane + 1;
            sel = true;
        }
    }

    unsigned word = 0;
    for (int c = 0; c < C; ++c) {
        const int ic = __shfl(idx, c);
        const int sc = __shfl((int)sel, c);
        if (sc && (ic >> 5) == lane) word |= 1u << (ic & 31);
    }
    return word;
}

// Bulk writer (R9-identical): per wave, build both row images in registers once,
// then 16 rows x 8 regular dwordx4 stores with only SGPR bit tests between bursts.
__global__ __launch_bounds__(256) void fill_kernel(
    const float* __restrict__ emb_s,
    const float* __restrict__ emb_t,
    const int* __restrict__ candidx,
    const unsigned* __restrict__ basemask,
    const unsigned* __restrict__ signw,
    const unsigned* __restrict__ specialw,
    float* __restrict__ dst)
{
    const int lane = threadIdx.x & 63;
    const int wave = threadIdx.x >> 6;
    const int rowbase = blockIdx.x * 64 + wave * 16;   // 16 consecutive rows
    const int g = rowbase >> 11;

    const unsigned sw = __builtin_amdgcn_readfirstlane(signw[rowbase >> 5]) >> (rowbase & 31);
    const unsigned pw = __builtin_amdgcn_readfirstlane(specialw[rowbase >> 5]) >> (rowbase & 31);

    const unsigned wpos = basemask[(2 * g + 0) * 64 + lane];
    const unsigned wneg = basemask[(2 * g + 1) * 64 + lane];
    floatx4 pos[8], neg[8];
    #pragma unroll
    for (int c = 0; c < 8; ++c) {
        const unsigned wp = (unsigned)__shfl((int)wpos, c * 8 + (lane >> 3));
        const unsigned wn = (unsigned)__shfl((int)wneg, c * 8 + (lane >> 3));
        const int b0 = (lane & 7) * 4;
        pos[c].x = (float)((wp >> (b0 + 0)) & 1u);
        pos[c].y = (float)((wp >> (b0 + 1)) & 1u);
        pos[c].z = (float)((wp >> (b0 + 2)) & 1u);
        pos[c].w = (float)((wp >> (b0 + 3)) & 1u);
        neg[c].x = (float)((wn >> (b0 + 0)) & 1u);
        neg[c].y = (float)((wn >> (b0 + 1)) & 1u);
        neg[c].z = (float)((wn >> (b0 + 2)) & 1u);
        neg[c].w = (float)((wn >> (b0 + 3)) & 1u);
    }

    #pragma unroll 1
    for (int r = 0; r < 16; ++r) {
        const int row = rowbase + r;
        floatx4* rp = reinterpret_cast<floatx4*>(dst + (size_t)row * N);
        if ((pw >> r) & 1u) {
            const unsigned word = row_word(emb_s, emb_t, candidx, row, lane);
            #pragma unroll
            for (int c = 0; c < 8; ++c) {
                const unsigned w = (unsigned)__shfl((int)word, c * 8 + (lane >> 3));
                const int b0 = (lane & 7) * 4;
                floatx4 v;
                v.x = (float)((w >> (b0 + 0)) & 1u);
                v.y = (float)((w >> (b0 + 1)) & 1u);
                v.z = (float)((w >> (b0 + 2)) & 1u);
                v.w = (float)((w >> (b0 + 3)) & 1u);
                *(rp + c * 64 + lane) = v;
            }
        } else if ((sw >> r) & 1u) {
            #pragma unroll
            for (int c = 0; c < 8; ++c)
                *(rp + c * 64 + lane) = neg[c];
        } else {
            #pragma unroll
            for (int c = 0; c < 8; ++c)
                *(rp + c * 64 + lane) = pos[c];
        }
    }
}

// PROBE: exact R6 zero_kernel structure (memset clone), but writing 256 MiB to
// d_ws. Its duration (= total - 107) discriminates buffer-cap vs kernel-cap.
__global__ __launch_bounds__(256) void probe_kernel(floatx4* __restrict__ dst) {
    const size_t total = (size_t)G * N * (N / 4);      // 16,777,216 float4s = 256 MiB
    const size_t stride = (size_t)gridDim.x * 256;
    const floatx4 z = {0.f, 0.f, 0.f, 0.f};
    for (size_t q = (size_t)blockIdx.x * 256 + threadIdx.x; q < total; q += stride)
        dst[q] = z;
}

extern "C" void kernel_launch(void* const* d_in, const int* in_sizes, int n_in,
                              void* d_out, int out_size, void* d_ws, size_t ws_size,
                              hipStream_t stream) {
    const float* emb_s = (const float*)d_in[0];   // (G, N, 1) f32
    const float* emb_t = (const float*)d_in[1];   // (G, 1, N) f32
    float* out = (float*)d_out;                   // (G, N, N) f32

    char* wsb = (char*)d_ws;
    int* candidx        = (int*)wsb;                     // 2560 B
    float* boundary     = (float*)(wsb + 4096);          // 256 B
    unsigned* basemask  = (unsigned*)(wsb + 8192);       // 8192 B
    unsigned* signw     = (unsigned*)(wsb + 16384);      // 4096 B
    unsigned* specialw  = (unsigned*)(wsb + 20480);      // 4096 B

    const size_t probeOff = (size_t)1 << 20;                       // 1 MiB
    const size_t probeBytes = (size_t)G * N * N * sizeof(float);   // 256 MiB

    // d_ws write-BW probe (single added variable vs R9).
    if (ws_size >= probeOff + probeBytes) {
        probe_kernel<<<2048, 256, 0, stream>>>((floatx4*)(wsb + probeOff));
    }

    // Proven R9 pipeline (107 µs) — output path untouched.
    topk_kernel<<<2 * G, 64, 0, stream>>>(emb_t, candidx, boundary, basemask);
    prep_kernel<<<128, 256, 0, stream>>>(emb_s, boundary, basemask, signw, specialw);
    fill_kernel<<<G * N / 64, 256, 0, stream>>>(emb_s, emb_t, candidx, basemask,
                                                signw, specialw, out);
}